// Round 4
// baseline (800.478 us; speedup 1.0000x reference)
//
#include <hip/hip_runtime.h>

typedef unsigned short u16;
typedef unsigned int u32;
typedef __bf16 bf16x8 __attribute__((ext_vector_type(8)));
typedef float f32x4 __attribute__((ext_vector_type(4)));

#define NV0 100000
#define NV1 50000
#define NV2 25000
#define NV3 12500

// workspace offsets (in u16 elements)
enum : long {
  OFF_WB0  = 0,
  OFF_WD1  = 27648,
  OFF_WB1  = 44032,
  OFF_WD2  = 154624,
  OFF_WB2  = 220160,
  OFF_WD3  = 662528,
  OFF_WB3  = 924672,
  OFF_WU2  = 2694144,
  OFF_WU1  = 2792448,
  OFF_WU0  = 2833408,
  OFF_WOUT = 2848768,
  OFF_TA   = 2897920,               // scratch x0a/x1a/x2a/x3a; later aliased by f32 tmp
  OFF_X0   = OFF_TA  + 3200000,
  OFF_X1   = OFF_X0  + 3200000,
  OFF_X2   = OFF_X1  + 3200000,
  OFF_X3   = OFF_X2  + 3200000,
  OFF_U2   = OFF_X3  + 3200000,
  OFF_U1   = OFF_U2  + 6400000,
  OFF_U0S  = OFF_U1  + 6400000,     // 8192*96 bf16
  OFF_END  = OFF_U0S + 786432,
};

__device__ __forceinline__ float b2f(u16 u) {
  union { u32 i; float f; } x; x.i = ((u32)u) << 16; return x.f;
}
__device__ __forceinline__ u16 f2b(float f) {
  union { float f; u32 i; } x; x.f = f;
  u32 r = (x.i + 0x7FFFu + ((x.i >> 16) & 1u)) >> 16;
  return (u16)r;
}
__device__ __forceinline__ void gload16(const u16* g, const u16* l) {
  __builtin_amdgcn_global_load_lds(
      (const __attribute__((address_space(1))) void*)g,
      (__attribute__((address_space(3))) void*)(u16*)l, 16, 0, 0);
}
__device__ __forceinline__ void store_out(u16* p, float v)  { *p = f2b(v); }
__device__ __forceinline__ void store_out(float* p, float v) { *p = v; }
constexpr int ilog2c(int x) { return x <= 1 ? 0 : 1 + ilog2c(x / 2); }

// ---------------- weight transpose prep: f32 W[k][c][o] -> bf16 Wt[k][o][c] ----------------
struct PD { const float* src; u16* dst; int KK, CIN, COUT; };
struct PrepArgs { PD d[11]; };

__global__ __launch_bounds__(256) void prep_k(PrepArgs pa) {
  const PD d = pa.d[blockIdx.y];
  const int cc = d.CIN * d.COUT;
  const int total = d.KK * cc;
  for (int e = blockIdx.x * 256 + threadIdx.x; e < total; e += gridDim.x * 256) {
    int k = e / cc;
    int r = e - k * cc;
    int c = r / d.COUT;
    int o = r - c * d.COUT;
    d.dst[(k * d.COUT + o) * d.CIN + c] = f2b(d.src[e]);
  }
}

// ---------------- stem: f32 [N0,3] gather-conv -> bf16 [N0,32], relu ----------------
__global__ __launch_bounds__(256) void stem_k(const float* __restrict__ feats,
                                              const int* __restrict__ nbr0,
                                              const float* __restrict__ wstem,
                                              u16* __restrict__ out) {
  __shared__ float Wl[27 * 3 * 32];
  const int tid = threadIdx.x;
  for (int i = tid; i < 2592; i += 256) Wl[i] = wstem[i];
  __syncthreads();
  const int n = blockIdx.x * 8 + (tid >> 5);
  const int o = tid & 31;
  if (n >= NV0) return;
  float acc = 0.f;
  const int* nb = nbr0 + n * 27;
  #pragma unroll
  for (int k = 0; k < 27; k++) {
    const int iv = nb[k];
    const float* f = feats + iv * 3;
    acc = fmaf(f[0], Wl[(k * 3 + 0) * 32 + o], acc);
    acc = fmaf(f[1], Wl[(k * 3 + 1) * 32 + o], acc);
    acc = fmaf(f[2], Wl[(k * 3 + 2) * 32 + o], acc);
  }
  out[n * 32 + o] = f2b(fmaxf(acc, 0.f));
}

// ---------------- generic MFMA gather-GEMM, dbuf + 1-barrier pipeline + swizzled LDS ----
// MODE 0: A(n,kc) = src0[idx0[n*KK + kc/CIN]*CIN + kc%CIN]      (sparse conv)
// MODE 1: kc<CA ? src0[idx0[n]*CA+kc] : src1[n*CB+kc-CA]        (upsample concat)
// MODE 2: s=idx0[n]; kc<CA ? src0[idx1[s]*CA+kc] : src1[s*CB+kc-CA] (seed concat)
// MODE 3: A = src0[n*KCT + kc]                                  (plain)
template <int BM, int BN, int WM, int WN, int COUTF, int KCT, int BK, int MODE,
          int CIN, int KK, int CA, bool RES, bool DORELU, typename OT>
__global__ __launch_bounds__(256, 3) void gemm_k(
    const u16* __restrict__ src0, const u16* __restrict__ src1,
    const int* __restrict__ idx0, const int* __restrict__ idx1,
    const u16* __restrict__ wt, const u16* __restrict__ base,
    OT* __restrict__ out, int N) {
  constexpr int NWM = BM / WM, NWN = BN / WN;
  static_assert(NWM * NWN == 4, "4 waves");
  constexpr int MI = WM / 16, NI = WN / 16;
  constexpr int CB = KCT - CA;
  constexpr int SLOTS = BK / 8;          // 16B slots per LDS row
  constexpr int SM = SLOTS - 1;
  constexpr int LSL = ilog2c(SLOTS);
  constexpr int RPC = 64 / SLOTS;        // rows per 1KB staging chunk
  constexpr int LRPC = ilog2c(RPC);
  constexpr int ACH = (BM * BK) / 512;   // A chunks
  constexpr int BCH = (BN * BK) / 512;
  constexpr int NIT = KCT / BK;
  constexpr int LOGC = ilog2c(CIN);
  static_assert(KCT % BK == 0, "K mult of BK");
  static_assert(MODE != 1 || (CA % BK == 0), "concat boundary aligned");

  __shared__ u16 As[2][BM * BK];
  __shared__ u16 Bs[2][BN * BK];
  const int tid = threadIdx.x;
  const int w = tid >> 6, lane = tid & 63;
  const int quad = lane >> 4, l16 = lane & 15;
  const int wm = w % NWM, wn = w / NWM;
  const int row0 = blockIdx.x * BM;
  const int col0 = blockIdx.y * BN;
  const int Nm1 = N - 1;
  // staging lane geometry (swizzled column group)
  const int srow = lane >> LSL;                    // row within chunk
  const int g    = (lane & SM) ^ (srow & SM);      // 16B group (logical col/8)
  const int cl   = g * 8;                          // col offset within BK

  f32x4 acc[MI][NI];
  #pragma unroll
  for (int i = 0; i < MI; i++)
    #pragma unroll
    for (int j = 0; j < NI; j++) acc[i][j] = {0.f, 0.f, 0.f, 0.f};

  auto stage = [&](int buf, int kc0) {
    for (int c = w; c < ACH + BCH; c += 4) {
      const int cab = kc0 + cl;
      if (c < ACH) {
        int n = row0 + (c << LRPC) + srow; n = (n > Nm1) ? Nm1 : n;
        const u16* gp;
        if constexpr (MODE == 0) {
          const int k = cab >> LOGC;
          gp = src0 + (long)idx0[n * KK + k] * CIN + (cab & (CIN - 1));
        } else if constexpr (MODE == 1) {
          if (kc0 < CA) gp = src0 + (long)idx0[n] * CA + cab;
          else          gp = src1 + (long)n * CB + (cab - CA);
        } else if constexpr (MODE == 2) {
          const int s = idx0[n];
          if (kc0 < CA) gp = src0 + (long)idx1[s] * CA + cab;
          else          gp = src1 + (long)s * CB + (cab - CA);
        } else {
          gp = src0 + (long)n * KCT + cab;
        }
        gload16(gp, &As[buf][c * 512]);
      } else {
        const int cb = c - ACH;
        const int o = col0 + (cb << LRPC) + srow;
        const u16* gp;
        if constexpr (MODE == 0) {
          const int k = cab >> LOGC;
          gp = wt + ((long)(k * COUTF + o)) * CIN + (cab & (CIN - 1));
        } else {
          gp = wt + (long)o * KCT + cab;
        }
        gload16(gp, &Bs[buf][cb * 512]);
      }
    }
  };

  stage(0, 0);
  #pragma unroll 1
  for (int it = 0; it < NIT; it++) {
    __syncthreads();                     // drains staging of buf it&1 (all waves)
    if (it + 1 < NIT) stage((it + 1) & 1, (it + 1) * BK);  // async prefetch
    const int buf = it & 1;
    #pragma unroll
    for (int kk = 0; kk < BK / 32; kk++) {
      bf16x8 af[MI], bfr[NI];
      #pragma unroll
      for (int i = 0; i < MI; i++) {
        const int row = wm * WM + i * 16 + l16;
        const int slot = row * SLOTS + (((kk << 2) + quad) ^ (row & SM));
        af[i] = *(const bf16x8*)&As[buf][slot * 8];
      }
      #pragma unroll
      for (int j = 0; j < NI; j++) {
        const int row = wn * WN + j * 16 + l16;
        const int slot = row * SLOTS + (((kk << 2) + quad) ^ (row & SM));
        bfr[j] = *(const bf16x8*)&Bs[buf][slot * 8];
      }
      #pragma unroll
      for (int i = 0; i < MI; i++)
        #pragma unroll
        for (int j = 0; j < NI; j++)
          acc[i][j] = __builtin_amdgcn_mfma_f32_16x16x32_bf16(af[i], bfr[j], acc[i][j], 0, 0, 0);
    }
  }

  // ---- epilogue: C/D layout col=lane&15, row=quad*4+reg ----
  #pragma unroll
  for (int i = 0; i < MI; i++) {
    #pragma unroll
    for (int j = 0; j < NI; j++) {
      const int col = col0 + wn * WN + j * 16 + l16;
      #pragma unroll
      for (int r = 0; r < 4; r++) {
        const int n = row0 + wm * WM + i * 16 + quad * 4 + r;
        if (n < N) {
          float v = acc[i][j][r];
          if constexpr (RES)         v = b2f(base[(long)n * COUTF + col]) + fmaxf(v, 0.f);
          else if constexpr (DORELU) v = fmaxf(v, 0.f);
          store_out(&out[(long)n * COUTF + col], v);
        }
      }
    }
  }
}

// ---------------- final transpose f32 tmp[8192][512] -> f32 out[8][512][1024] ----------------
__global__ __launch_bounds__(256) void tout_k(const float* __restrict__ tmp,
                                              float* __restrict__ outp) {
  __shared__ float tl[64][65];
  const int tid = threadIdx.x;
  const int r0 = blockIdx.x * 64, o0 = blockIdx.y * 64;
  {
    const int rl = tid >> 2, oc = (tid & 3) * 16;
    const float* src = &tmp[(r0 + rl) * 512 + o0 + oc];
    #pragma unroll
    for (int j = 0; j < 16; j++) tl[rl][oc + j] = src[j];
  }
  __syncthreads();
  {
    const int ol = tid >> 2, sc = (tid & 3) * 16;
    const int b = r0 >> 10, s0 = r0 & 1023;
    float* dst = &outp[((long)b * 512 + (o0 + ol)) * 1024 + s0 + sc];
    #pragma unroll
    for (int j = 0; j < 16; j++) dst[j] = tl[sc + j][ol];
  }
}

extern "C" void kernel_launch(void* const* d_in, const int* in_sizes, int n_in,
                              void* d_out, int out_size, void* d_ws, size_t ws_size,
                              hipStream_t stream) {
  const float* feats = (const float*)d_in[0];
  const int* nbr0  = (const int*)d_in[1];
  const int* nbr1  = (const int*)d_in[2];
  const int* nbr2  = (const int*)d_in[3];
  const int* nbr3  = (const int*)d_in[4];
  const int* down1 = (const int*)d_in[5];
  const int* down2 = (const int*)d_in[6];
  const int* down3 = (const int*)d_in[7];
  const int* up2   = (const int*)d_in[8];
  const int* up1   = (const int*)d_in[9];
  const int* up0   = (const int*)d_in[10];
  const int* seed  = (const int*)d_in[11];
  u16* ws = (u16*)d_ws;

  PrepArgs pa;
  pa.d[0]  = {(const float*)d_in[13], ws + OFF_WB0,  27, 32, 32};
  pa.d[1]  = {(const float*)d_in[14], ws + OFF_WD1,  8,  32, 64};
  pa.d[2]  = {(const float*)d_in[15], ws + OFF_WB1,  27, 64, 64};
  pa.d[3]  = {(const float*)d_in[16], ws + OFF_WD2,  8,  64, 128};
  pa.d[4]  = {(const float*)d_in[17], ws + OFF_WB2,  27, 128, 128};
  pa.d[5]  = {(const float*)d_in[18], ws + OFF_WD3,  8,  128, 256};
  pa.d[6]  = {(const float*)d_in[19], ws + OFF_WB3,  27, 256, 256};
  pa.d[7]  = {(const float*)d_in[20], ws + OFF_WU2,  1,  384, 256};
  pa.d[8]  = {(const float*)d_in[21], ws + OFF_WU1,  1,  320, 128};
  pa.d[9]  = {(const float*)d_in[22], ws + OFF_WU0,  1,  160, 96};
  pa.d[10] = {(const float*)d_in[23], ws + OFF_WOUT, 1,  96,  512};
  prep_k<<<dim3(128, 11), 256, 0, stream>>>(pa);

  u16* ta  = ws + OFF_TA;
  u16* x0  = ws + OFF_X0;
  u16* x1  = ws + OFF_X1;
  u16* x2  = ws + OFF_X2;
  u16* x3  = ws + OFF_X3;
  u16* u2b = ws + OFF_U2;
  u16* u1b = ws + OFF_U1;
  u16* u0s = ws + OFF_U0S;
  float* tmp = (float*)(ws + OFF_TA);   // aliases TA/X0/X1 (dead by the time s2 runs)

  stem_k<<<12500, 256, 0, stream>>>(feats, nbr0, (const float*)d_in[12], ta);

  // b0: x0 = x0a + relu(conv(x0a, nbr0, W_b0))     [100000 x 32], K=864
  gemm_k<128, 32, 32, 32, 32, 864, 32, 0, 32, 27, 0, true, true, u16>
      <<<dim3(782, 1), 256, 0, stream>>>(ta, nullptr, nbr0, nullptr, ws + OFF_WB0, ta, x0, NV0);
  // d1: x1a = relu(conv(x0, down1, W_d1))          [50000 x 64], K=256
  gemm_k<128, 64, 64, 32, 64, 256, 64, 0, 32, 8, 0, false, true, u16>
      <<<dim3(391, 1), 256, 0, stream>>>(x0, nullptr, down1, nullptr, ws + OFF_WD1, nullptr, ta, NV1);
  // b1                                             [50000 x 64], K=1728
  gemm_k<128, 64, 64, 32, 64, 1728, 64, 0, 64, 27, 0, true, true, u16>
      <<<dim3(391, 1), 256, 0, stream>>>(ta, nullptr, nbr1, nullptr, ws + OFF_WB1, ta, x1, NV1);
  // d2                                             [25000 x 128], K=512
  gemm_k<64, 128, 32, 64, 128, 512, 64, 0, 64, 8, 0, false, true, u16>
      <<<dim3(391, 1), 256, 0, stream>>>(x1, nullptr, down2, nullptr, ws + OFF_WD2, nullptr, ta, NV2);
  // b2                                             [25000 x 128], K=3456
  gemm_k<64, 128, 32, 64, 128, 3456, 64, 0, 128, 27, 0, true, true, u16>
      <<<dim3(391, 1), 256, 0, stream>>>(ta, nullptr, nbr2, nullptr, ws + OFF_WB2, ta, x2, NV2);
  // d3                                             [12500 x 256], K=1024
  gemm_k<64, 128, 32, 64, 256, 1024, 64, 0, 128, 8, 0, false, true, u16>
      <<<dim3(196, 2), 256, 0, stream>>>(x2, nullptr, down3, nullptr, ws + OFF_WD3, nullptr, ta, NV3);
  // b3                                             [12500 x 256], K=6912
  gemm_k<64, 128, 32, 64, 256, 6912, 64, 0, 256, 27, 0, true, true, u16>
      <<<dim3(196, 2), 256, 0, stream>>>(ta, nullptr, nbr3, nullptr, ws + OFF_WB3, ta, x3, NV3);
  // u2 = relu(cat(x3[up2], x2) @ W_u2)             [25000 x 256], K=384
  gemm_k<64, 128, 32, 64, 256, 384, 64, 1, 32, 1, 256, false, true, u16>
      <<<dim3(391, 2), 256, 0, stream>>>(x3, x2, up2, nullptr, ws + OFF_WU2, nullptr, u2b, NV2);
  // u1 = relu(cat(u2[up1], x1) @ W_u1)             [50000 x 128], K=320
  gemm_k<64, 128, 32, 64, 128, 320, 64, 1, 32, 1, 256, false, true, u16>
      <<<dim3(782, 1), 256, 0, stream>>>(u2b, x1, up1, nullptr, ws + OFF_WU1, nullptr, u1b, NV1);
  // s1: per-seed u0 = relu(cat(u1[up0[seed]], x0[seed]) @ W_u0)  [8192 x 96], K=160
  gemm_k<64, 96, 32, 48, 96, 160, 32, 2, 32, 1, 128, false, true, u16>
      <<<dim3(128, 1), 256, 0, stream>>>(u1b, x0, seed, up0, ws + OFF_WU0, nullptr, u0s, 8192);
  // s2: tmp = u0s @ W_out                          [8192 x 512] f32, K=96
  gemm_k<64, 128, 32, 64, 512, 96, 32, 3, 32, 1, 0, false, false, float>
      <<<dim3(128, 4), 256, 0, stream>>>(u0s, nullptr, nullptr, nullptr, ws + OFF_WOUT, nullptr, tmp, 8192);
  // transpose to [B, 512, S] f32
  tout_k<<<dim3(128, 8), 256, 0, stream>>>(tmp, (float*)d_out);
}

// Round 5
// 527.688 us; speedup vs baseline: 1.5170x; 1.5170x over previous
//
#include <hip/hip_runtime.h>

typedef unsigned short u16;
typedef unsigned int u32;
typedef __bf16 bf16x8 __attribute__((ext_vector_type(8)));
typedef float f32x4 __attribute__((ext_vector_type(4)));

#define NV0 100000
#define NV1 50000
#define NV2 25000
#define NV3 12500

// workspace offsets (in u16 elements)
enum : long {
  OFF_WB0  = 0,
  OFF_WD1  = 27648,
  OFF_WB1  = 44032,
  OFF_WD2  = 154624,
  OFF_WB2  = 220160,
  OFF_WD3  = 662528,
  OFF_WB3  = 924672,
  OFF_WU2  = 2694144,
  OFF_WU1  = 2792448,
  OFF_WU0  = 2833408,
  OFF_WOUT = 2848768,
  OFF_TA   = 2897920,               // scratch x0a/x1a/x2a/x3a; later aliased by f32 tmp
  OFF_X0   = OFF_TA  + 3200000,
  OFF_X1   = OFF_X0  + 3200000,
  OFF_X2   = OFF_X1  + 3200000,
  OFF_X3   = OFF_X2  + 3200000,
  OFF_U2   = OFF_X3  + 3200000,
  OFF_U1   = OFF_U2  + 6400000,
  OFF_U0S  = OFF_U1  + 6400000,     // 8192*96 bf16
  OFF_END  = OFF_U0S + 786432,
};

__device__ __forceinline__ float b2f(u16 u) {
  union { u32 i; float f; } x; x.i = ((u32)u) << 16; return x.f;
}
__device__ __forceinline__ u16 f2b(float f) {
  union { float f; u32 i; } x; x.f = f;
  u32 r = (x.i + 0x7FFFu + ((x.i >> 16) & 1u)) >> 16;
  return (u16)r;
}
__device__ __forceinline__ void gload16(const u16* g, const u16* l) {
  __builtin_amdgcn_global_load_lds(
      (const __attribute__((address_space(1))) void*)g,
      (__attribute__((address_space(3))) void*)(u16*)l, 16, 0, 0);
}
__device__ __forceinline__ void store_out(u16* p, float v)  { *p = f2b(v); }
__device__ __forceinline__ void store_out(float* p, float v) { *p = v; }
constexpr int ilog2c(int x) { return x <= 1 ? 0 : 1 + ilog2c(x / 2); }

// ---------------- weight transpose prep: f32 W[k][c][o] -> bf16 Wt[k][o][c] ----------------
struct PD { const float* src; u16* dst; int KK, CIN, COUT; };
struct PrepArgs { PD d[11]; };

__global__ __launch_bounds__(256) void prep_k(PrepArgs pa) {
  const PD d = pa.d[blockIdx.y];
  const int cc = d.CIN * d.COUT;
  const int total = d.KK * cc;
  for (int e = blockIdx.x * 256 + threadIdx.x; e < total; e += gridDim.x * 256) {
    int k = e / cc;
    int r = e - k * cc;
    int c = r / d.COUT;
    int o = r - c * d.COUT;
    d.dst[(k * d.COUT + o) * d.CIN + c] = f2b(d.src[e]);
  }
}

// ---------------- stem: f32 [N0,3] gather-conv -> bf16 [N0,32], relu ----------------
__global__ __launch_bounds__(256) void stem_k(const float* __restrict__ feats,
                                              const int* __restrict__ nbr0,
                                              const float* __restrict__ wstem,
                                              u16* __restrict__ out) {
  __shared__ float Wl[27 * 3 * 32];
  const int tid = threadIdx.x;
  for (int i = tid; i < 2592; i += 256) Wl[i] = wstem[i];
  __syncthreads();
  const int n = blockIdx.x * 8 + (tid >> 5);
  const int o = tid & 31;
  if (n >= NV0) return;
  float acc = 0.f;
  const int* nb = nbr0 + n * 27;
  #pragma unroll
  for (int k = 0; k < 27; k++) {
    const int iv = nb[k];
    const float* f = feats + iv * 3;
    acc = fmaf(f[0], Wl[(k * 3 + 0) * 32 + o], acc);
    acc = fmaf(f[1], Wl[(k * 3 + 1) * 32 + o], acc);
    acc = fmaf(f[2], Wl[(k * 3 + 2) * 32 + o], acc);
  }
  out[n * 32 + o] = f2b(fmaxf(acc, 0.f));
}

// ---------------- generic MFMA gather-GEMM, dbuf + 1-barrier pipeline + swizzled LDS ----
// Indices for the block's rows are preloaded into LDS (Is) once — staging reads them
// via ds_read instead of a dependent global load each iteration.
// MODE 0: A(n,kc) = src0[idx0[n*KK + kc/CIN]*CIN + kc%CIN]      (sparse conv)
// MODE 1: kc<CA ? src0[idx0[n]*CA+kc] : src1[n*CB+kc-CA]        (upsample concat)
// MODE 2: s=idx0[n]; kc<CA ? src0[idx1[s]*CA+kc] : src1[s*CB+kc-CA] (seed concat)
// MODE 3: A = src0[n*KCT + kc]                                  (plain)
template <int BM, int BN, int WM, int WN, int COUTF, int KCT, int BK, int MODE,
          int CIN, int KK, int CA, bool RES, bool DORELU, typename OT>
__global__ __launch_bounds__(256, 4) void gemm_k(
    const u16* __restrict__ src0, const u16* __restrict__ src1,
    const int* __restrict__ idx0, const int* __restrict__ idx1,
    const u16* __restrict__ wt, const u16* __restrict__ base,
    OT* __restrict__ out, int N) {
  constexpr int NWM = BM / WM, NWN = BN / WN;
  static_assert(NWM * NWN == 4, "4 waves");
  constexpr int MI = WM / 16, NI = WN / 16;
  constexpr int CB = KCT - CA;
  constexpr int SLOTS = BK / 8;          // 16B slots per LDS row
  constexpr int SM = SLOTS - 1;
  constexpr int LSL = ilog2c(SLOTS);
  constexpr int RPC = 64 / SLOTS;        // rows per 1KB staging chunk
  constexpr int LRPC = ilog2c(RPC);
  constexpr int ACH = (BM * BK) / 512;   // A chunks
  constexpr int BCH = (BN * BK) / 512;
  constexpr int NIT = KCT / BK;
  constexpr int LOGC = ilog2c(CIN);
  constexpr int NIDX = (MODE == 0) ? BM * KK : (MODE == 1 ? BM : (MODE == 2 ? 2 * BM : 1));
  static_assert(KCT % BK == 0, "K mult of BK");
  static_assert(MODE != 1 || (CA % BK == 0), "concat boundary aligned");

  __shared__ u16 As[2][BM * BK];
  __shared__ u16 Bs[2][BN * BK];
  __shared__ int Is[NIDX];
  const int tid = threadIdx.x;
  const int w = tid >> 6, lane = tid & 63;
  const int quad = lane >> 4, l16 = lane & 15;
  const int wm = w % NWM, wn = w / NWM;
  const int row0 = blockIdx.x * BM;
  const int col0 = blockIdx.y * BN;
  const int Nm1 = N - 1;
  // staging lane geometry (swizzled column group)
  const int srow = lane >> LSL;                    // row within chunk
  const int g    = (lane & SM) ^ (srow & SM);      // 16B group (logical col/8)
  const int cl   = g * 8;                          // col offset within BK

  // ---- preload per-row gather indices into LDS ----
  if constexpr (MODE == 0) {
    for (int e = tid; e < BM * KK; e += 256) {
      const int r = e / KK, k = e - r * KK;
      int n = row0 + r; n = (n > Nm1) ? Nm1 : n;
      Is[e] = idx0[(long)n * KK + k];
    }
  } else if constexpr (MODE == 1) {
    for (int e = tid; e < BM; e += 256) {
      int n = row0 + e; n = (n > Nm1) ? Nm1 : n;
      Is[e] = idx0[n];
    }
  } else if constexpr (MODE == 2) {
    for (int e = tid; e < BM; e += 256) {
      int n = row0 + e; n = (n > Nm1) ? Nm1 : n;
      const int s = idx0[n];
      Is[e] = idx1[s];
      Is[BM + e] = s;
    }
  }
  if constexpr (MODE != 3) __syncthreads();

  f32x4 acc[MI][NI];
  #pragma unroll
  for (int i = 0; i < MI; i++)
    #pragma unroll
    for (int j = 0; j < NI; j++) acc[i][j] = {0.f, 0.f, 0.f, 0.f};

  auto stage = [&](int buf, int kc0) {
    for (int c = w; c < ACH + BCH; c += 4) {
      const int cab = kc0 + cl;
      if (c < ACH) {
        const int r = (c << LRPC) + srow;          // local row, < BM
        const u16* gp;
        if constexpr (MODE == 0) {
          const int k = cab >> LOGC;
          gp = src0 + (long)Is[r * KK + k] * CIN + (cab & (CIN - 1));
        } else if constexpr (MODE == 1) {
          if (kc0 < CA) gp = src0 + (long)Is[r] * CA + cab;
          else {
            int n = row0 + r; n = (n > Nm1) ? Nm1 : n;
            gp = src1 + (long)n * CB + (cab - CA);
          }
        } else if constexpr (MODE == 2) {
          if (kc0 < CA) gp = src0 + (long)Is[r] * CA + cab;
          else          gp = src1 + (long)Is[BM + r] * CB + (cab - CA);
        } else {
          int n = row0 + r; n = (n > Nm1) ? Nm1 : n;
          gp = src0 + (long)n * KCT + cab;
        }
        gload16(gp, &As[buf][c * 512]);
      } else {
        const int cb = c - ACH;
        const int o = col0 + (cb << LRPC) + srow;
        const u16* gp;
        if constexpr (MODE == 0) {
          const int k = cab >> LOGC;
          gp = wt + ((long)(k * COUTF + o)) * CIN + (cab & (CIN - 1));
        } else {
          gp = wt + (long)o * KCT + cab;
        }
        gload16(gp, &Bs[buf][cb * 512]);
      }
    }
  };

  stage(0, 0);
  #pragma unroll 1
  for (int it = 0; it < NIT; it++) {
    __syncthreads();                     // drains staging of buf it&1 (all waves)
    if (it + 1 < NIT) stage((it + 1) & 1, (it + 1) * BK);  // async prefetch
    const int buf = it & 1;
    #pragma unroll
    for (int kk = 0; kk < BK / 32; kk++) {
      bf16x8 af[MI], bfr[NI];
      #pragma unroll
      for (int i = 0; i < MI; i++) {
        const int row = wm * WM + i * 16 + l16;
        const int slot = row * SLOTS + (((kk << 2) + quad) ^ (row & SM));
        af[i] = *(const bf16x8*)&As[buf][slot * 8];
      }
      #pragma unroll
      for (int j = 0; j < NI; j++) {
        const int row = wn * WN + j * 16 + l16;
        const int slot = row * SLOTS + (((kk << 2) + quad) ^ (row & SM));
        bfr[j] = *(const bf16x8*)&Bs[buf][slot * 8];
      }
      #pragma unroll
      for (int i = 0; i < MI; i++)
        #pragma unroll
        for (int j = 0; j < NI; j++)
          acc[i][j] = __builtin_amdgcn_mfma_f32_16x16x32_bf16(af[i], bfr[j], acc[i][j], 0, 0, 0);
    }
  }

  // ---- epilogue: C/D layout col=lane&15, row=quad*4+reg ----
  #pragma unroll
  for (int i = 0; i < MI; i++) {
    #pragma unroll
    for (int j = 0; j < NI; j++) {
      const int col = col0 + wn * WN + j * 16 + l16;
      #pragma unroll
      for (int r = 0; r < 4; r++) {
        const int n = row0 + wm * WM + i * 16 + quad * 4 + r;
        if (n < N) {
          float v = acc[i][j][r];
          if constexpr (RES)         v = b2f(base[(long)n * COUTF + col]) + fmaxf(v, 0.f);
          else if constexpr (DORELU) v = fmaxf(v, 0.f);
          store_out(&out[(long)n * COUTF + col], v);
        }
      }
    }
  }
}

// ---------------- final transpose f32 tmp[8192][512] -> f32 out[8][512][1024] ----------------
__global__ __launch_bounds__(256) void tout_k(const float* __restrict__ tmp,
                                              float* __restrict__ outp) {
  __shared__ float tl[64][65];
  const int tid = threadIdx.x;
  const int r0 = blockIdx.x * 64, o0 = blockIdx.y * 64;
  {
    const int rl = tid >> 2, oc = (tid & 3) * 16;
    const float* src = &tmp[(r0 + rl) * 512 + o0 + oc];
    #pragma unroll
    for (int j = 0; j < 16; j++) tl[rl][oc + j] = src[j];
  }
  __syncthreads();
  {
    const int ol = tid >> 2, sc = (tid & 3) * 16;
    const int b = r0 >> 10, s0 = r0 & 1023;
    float* dst = &outp[((long)b * 512 + (o0 + ol)) * 1024 + s0 + sc];
    #pragma unroll
    for (int j = 0; j < 16; j++) dst[j] = tl[sc + j][ol];
  }
}

extern "C" void kernel_launch(void* const* d_in, const int* in_sizes, int n_in,
                              void* d_out, int out_size, void* d_ws, size_t ws_size,
                              hipStream_t stream) {
  const float* feats = (const float*)d_in[0];
  const int* nbr0  = (const int*)d_in[1];
  const int* nbr1  = (const int*)d_in[2];
  const int* nbr2  = (const int*)d_in[3];
  const int* nbr3  = (const int*)d_in[4];
  const int* down1 = (const int*)d_in[5];
  const int* down2 = (const int*)d_in[6];
  const int* down3 = (const int*)d_in[7];
  const int* up2   = (const int*)d_in[8];
  const int* up1   = (const int*)d_in[9];
  const int* up0   = (const int*)d_in[10];
  const int* seed  = (const int*)d_in[11];
  u16* ws = (u16*)d_ws;

  PrepArgs pa;
  pa.d[0]  = {(const float*)d_in[13], ws + OFF_WB0,  27, 32, 32};
  pa.d[1]  = {(const float*)d_in[14], ws + OFF_WD1,  8,  32, 64};
  pa.d[2]  = {(const float*)d_in[15], ws + OFF_WB1,  27, 64, 64};
  pa.d[3]  = {(const float*)d_in[16], ws + OFF_WD2,  8,  64, 128};
  pa.d[4]  = {(const float*)d_in[17], ws + OFF_WB2,  27, 128, 128};
  pa.d[5]  = {(const float*)d_in[18], ws + OFF_WD3,  8,  128, 256};
  pa.d[6]  = {(const float*)d_in[19], ws + OFF_WB3,  27, 256, 256};
  pa.d[7]  = {(const float*)d_in[20], ws + OFF_WU2,  1,  384, 256};
  pa.d[8]  = {(const float*)d_in[21], ws + OFF_WU1,  1,  320, 128};
  pa.d[9]  = {(const float*)d_in[22], ws + OFF_WU0,  1,  160, 96};
  pa.d[10] = {(const float*)d_in[23], ws + OFF_WOUT, 1,  96,  512};
  prep_k<<<dim3(128, 11), 256, 0, stream>>>(pa);

  u16* ta  = ws + OFF_TA;
  u16* x0  = ws + OFF_X0;
  u16* x1  = ws + OFF_X1;
  u16* x2  = ws + OFF_X2;
  u16* x3  = ws + OFF_X3;
  u16* u2b = ws + OFF_U2;
  u16* u1b = ws + OFF_U1;
  u16* u0s = ws + OFF_U0S;
  float* tmp = (float*)(ws + OFF_TA);   // aliases TA/X0/X1 (dead by the time s2 runs)

  stem_k<<<12500, 256, 0, stream>>>(feats, nbr0, (const float*)d_in[12], ta);

  // b0: x0 = x0a + relu(conv(x0a, nbr0, W_b0))     [100000 x 32], K=864
  gemm_k<128, 32, 32, 32, 32, 864, 32, 0, 32, 27, 0, true, true, u16>
      <<<dim3(782, 1), 256, 0, stream>>>(ta, nullptr, nbr0, nullptr, ws + OFF_WB0, ta, x0, NV0);
  // d1: x1a = relu(conv(x0, down1, W_d1))          [50000 x 64], K=256
  gemm_k<64, 64, 32, 32, 64, 256, 64, 0, 32, 8, 0, false, true, u16>
      <<<dim3(782, 1), 256, 0, stream>>>(x0, nullptr, down1, nullptr, ws + OFF_WD1, nullptr, ta, NV1);
  // b1                                             [50000 x 64], K=1728
  gemm_k<64, 64, 32, 32, 64, 1728, 64, 0, 64, 27, 0, true, true, u16>
      <<<dim3(782, 1), 256, 0, stream>>>(ta, nullptr, nbr1, nullptr, ws + OFF_WB1, ta, x1, NV1);
  // d2                                             [25000 x 128], K=512
  gemm_k<64, 64, 32, 32, 128, 512, 64, 0, 64, 8, 0, false, true, u16>
      <<<dim3(391, 2), 256, 0, stream>>>(x1, nullptr, down2, nullptr, ws + OFF_WD2, nullptr, ta, NV2);
  // b2                                             [25000 x 128], K=3456
  gemm_k<64, 64, 32, 32, 128, 3456, 64, 0, 128, 27, 0, true, true, u16>
      <<<dim3(391, 2), 256, 0, stream>>>(ta, nullptr, nbr2, nullptr, ws + OFF_WB2, ta, x2, NV2);
  // d3                                             [12500 x 256], K=1024
  gemm_k<64, 64, 32, 32, 256, 1024, 64, 0, 128, 8, 0, false, true, u16>
      <<<dim3(196, 4), 256, 0, stream>>>(x2, nullptr, down3, nullptr, ws + OFF_WD3, nullptr, ta, NV3);
  // b3                                             [12500 x 256], K=6912
  gemm_k<64, 64, 32, 32, 256, 6912, 64, 0, 256, 27, 0, true, true, u16>
      <<<dim3(196, 4), 256, 0, stream>>>(ta, nullptr, nbr3, nullptr, ws + OFF_WB3, ta, x3, NV3);
  // u2 = relu(cat(x3[up2], x2) @ W_u2)             [25000 x 256], K=384
  gemm_k<64, 64, 32, 32, 256, 384, 64, 1, 32, 1, 256, false, true, u16>
      <<<dim3(391, 4), 256, 0, stream>>>(x3, x2, up2, nullptr, ws + OFF_WU2, nullptr, u2b, NV2);
  // u1 = relu(cat(u2[up1], x1) @ W_u1)             [50000 x 128], K=320
  gemm_k<64, 64, 32, 32, 128, 320, 64, 1, 32, 1, 256, false, true, u16>
      <<<dim3(782, 2), 256, 0, stream>>>(u2b, x1, up1, nullptr, ws + OFF_WU1, nullptr, u1b, NV1);
  // s1: per-seed u0 = relu(cat(u1[up0[seed]], x0[seed]) @ W_u0)  [8192 x 96], K=160
  gemm_k<64, 96, 32, 48, 96, 160, 32, 2, 32, 1, 128, false, true, u16>
      <<<dim3(128, 1), 256, 0, stream>>>(u1b, x0, seed, up0, ws + OFF_WU0, nullptr, u0s, 8192);
  // s2: tmp = u0s @ W_out                          [8192 x 512] f32, K=96
  gemm_k<64, 64, 32, 32, 512, 96, 32, 3, 32, 1, 0, false, false, float>
      <<<dim3(128, 8), 256, 0, stream>>>(u0s, nullptr, nullptr, nullptr, ws + OFF_WOUT, nullptr, tmp, 8192);
  // transpose to [B, 512, S] f32
  tout_k<<<dim3(128, 8), 256, 0, stream>>>(tmp, (float*)d_out);
}